// Round 11
// baseline (61.130 us; speedup 1.0000x reference)
//
#include <hip/hip_runtime.h>
#include <hip/hip_bf16.h>

#define DNBR   16
#define INDIM  128
#define OUTDIM 64

typedef __attribute__((ext_vector_type(8))) short bf16x8;
typedef __attribute__((ext_vector_type(4))) float f32x4;
typedef __attribute__((ext_vector_type(4))) unsigned u32x4;

union BF8 { bf16x8 v; u32x4 u; };

__device__ __forceinline__ unsigned cvt_pk_bf16(float lo, float hi) {
    unsigned r;
    asm("v_cvt_pk_bf16_f32 %0, %1, %2" : "=v"(r) : "v"(lo), "v"(hi));
    return r;
}

// ---------------- Phase 1: z = h @ W_fc^T via bf16 MFMA, + s_src/s_dst -------
// W_fc converted to MFMA B-fragment order in LDS per block.
__global__ __launch_bounds__(256) void fc_mfma(
    const float* __restrict__ h, const float* __restrict__ W_fc,
    const float* __restrict__ W_attn, __hip_bfloat16* __restrict__ zb,
    float* __restrict__ s_src, float* __restrict__ s_dst, int n)
{
    __shared__ unsigned wl[4096];   // 16 KB: slot(ct,kk,lane) -> 4 u32 (8 bf16)

    const int tid = threadIdx.x;
    #pragma unroll
    for (int s4 = 0; s4 < 4; ++s4) {
        const int slot = tid + 256 * s4;      // 0..1023
        const int lane_s = slot & 63;
        const int ckk  = slot >> 6;           // ct*4+kk
        const int ct_s = ckk >> 2, kk_s = ckk & 3;
        const int lm_s = lane_s & 15, lg_s = lane_s >> 4;
        const float* wr = W_fc + (size_t)(ct_s * 16 + lm_s) * INDIM + kk_s * 32 + lg_s * 8;
        const float4 w0 = *reinterpret_cast<const float4*>(wr);
        const float4 w1 = *reinterpret_cast<const float4*>(wr + 4);
        wl[slot * 4 + 0] = cvt_pk_bf16(w0.x, w0.y);
        wl[slot * 4 + 1] = cvt_pk_bf16(w0.z, w0.w);
        wl[slot * 4 + 2] = cvt_pk_bf16(w1.x, w1.y);
        wl[slot * 4 + 3] = cvt_pk_bf16(w1.z, w1.w);
    }
    __syncthreads();

    const int lane  = threadIdx.x & 63;
    const int wid   = threadIdx.x >> 6;
    const int node0 = blockIdx.x * 64 + wid * 16;
    if (node0 >= n) return;
    const int lm = lane & 15;
    const int lg = lane >> 4;

    bf16x8 bfrag[4][4];
    #pragma unroll
    for (int ct = 0; ct < 4; ++ct)
        #pragma unroll
        for (int kk = 0; kk < 4; ++kk) {
            BF8 u;
            u.u = *reinterpret_cast<const u32x4*>(&wl[(size_t)((ct * 4 + kk) * 64 + lane) * 4]);
            bfrag[ct][kk] = u.v;
        }

    const int arow = (node0 + lm < n) ? (node0 + lm) : (n - 1);
    const float* hr = h + (size_t)arow * INDIM;
    bf16x8 af[4];
    #pragma unroll
    for (int kk = 0; kk < 4; ++kk) {
        const float4 a0 = *reinterpret_cast<const float4*>(hr + kk * 32 + lg * 8);
        const float4 a1 = *reinterpret_cast<const float4*>(hr + kk * 32 + lg * 8 + 4);
        BF8 u;
        u.u[0] = cvt_pk_bf16(a0.x, a0.y);
        u.u[1] = cvt_pk_bf16(a0.z, a0.w);
        u.u[2] = cvt_pk_bf16(a1.x, a1.y);
        u.u[3] = cvt_pk_bf16(a1.z, a1.w);
        af[kk] = u.v;
    }

    f32x4 acc[4];
    #pragma unroll
    for (int ct = 0; ct < 4; ++ct) acc[ct] = (f32x4){0.f, 0.f, 0.f, 0.f};
    #pragma unroll
    for (int kk = 0; kk < 4; ++kk)
        #pragma unroll
        for (int ct = 0; ct < 4; ++ct)
            acc[ct] = __builtin_amdgcn_mfma_f32_16x16x32_bf16(af[kk], bfrag[ct][kk], acc[ct], 0, 0, 0);

    float ps[4] = {0.f, 0.f, 0.f, 0.f};
    float pd[4] = {0.f, 0.f, 0.f, 0.f};
    unsigned short* zbs = reinterpret_cast<unsigned short*>(zb);
    #pragma unroll
    for (int ct = 0; ct < 4; ++ct) {
        const float as = W_attn[ct * 16 + lm];
        const float ad = W_attn[OUTDIM + ct * 16 + lm];
        #pragma unroll
        for (int r = 0; r < 4; ++r) {
            const float v = acc[ct][r];                 // C[(lg*4+r)][ct*16+lm]
            const int grow = node0 + lg * 4 + r;
            if (grow < n)
                zbs[(size_t)grow * OUTDIM + ct * 16 + lm] =
                    (unsigned short)(cvt_pk_bf16(v, v) & 0xFFFFu);
            ps[r] = fmaf(v, as, ps[r]);
            pd[r] = fmaf(v, ad, pd[r]);
        }
    }
    #pragma unroll
    for (int off = 1; off < 16; off <<= 1) {
        #pragma unroll
        for (int r = 0; r < 4; ++r) {
            ps[r] += __shfl_xor(ps[r], off, 64);
            pd[r] += __shfl_xor(pd[r], off, 64);
        }
    }
    if (lm == 0) {
        #pragma unroll
        for (int r = 0; r < 4; ++r) {
            const int grow = node0 + lg * 4 + r;
            if (grow < n) { s_src[grow] = ps[r]; s_dst[grow] = pd[r]; }
        }
    }
}

// ---------------- Phase 2: fused, 2-batch software-pipelined -----------------
// Wave owns 8 nodes (2 batches of 4). Per batch: lane-parallel entmax
// (16-lane group per node) -> LDS slice; z-gathers issued into registers
// BEFORE the next batch's entmax so latency hides under its VALU/shfl chain.
__global__ __launch_bounds__(256) void fused_out(
    const int* __restrict__ nbr, const float* __restrict__ wbias,
    const __hip_bfloat16* __restrict__ zb, const float* __restrict__ s_src,
    const float* __restrict__ s_dst, float* __restrict__ out, int n)
{
    __shared__ float w_lds[4][2][64];
    __shared__ int  nb_lds[4][2][64];

    const int lane = threadIdx.x & 63;
    const int wid  = threadIdx.x >> 6;
    const int wv   = blockIdx.x * 4 + wid;
    const int base0 = wv * 8;
    if (base0 >= n) return;
    const int base1 = base0 + 4;
    const int g  = lane >> 3;
    const int c8 = lane & 7;
    const unsigned short* zs = reinterpret_cast<const unsigned short*>(zb);

    // ---- lane-parallel entmax for 4 nodes starting at BASE -> LDS slice BUF
    #define ENTMAX(BASE, BUF)                                                   \
    {                                                                           \
        const int q = lane >> 4;                                                \
        const int j = lane & 15;                                                \
        const int gb = lane & 48;                                               \
        const int node_q = (BASE) + q;                                          \
        const int nq = (node_q < n) ? node_q : n - 1;                           \
        const int   nbj = nbr  [(size_t)nq * DNBR + j];                         \
        const float wj  = wbias[(size_t)nq * DNBR + j];                         \
        const float sd  = s_dst[nq];                                            \
        float e = s_src[nbj] + sd;                                              \
        e = (e >= 0.f) ? e : 0.01f * e;                                         \
        float x = 0.5f * (e + wj);                                              \
        float m = x;                                                            \
        m = fmaxf(m, __shfl_xor(m, 1, 64));                                     \
        m = fmaxf(m, __shfl_xor(m, 2, 64));                                     \
        m = fmaxf(m, __shfl_xor(m, 4, 64));                                     \
        m = fmaxf(m, __shfl_xor(m, 8, 64));                                     \
        x -= m;                                                                 \
        float v = x;                                                            \
        _Pragma("unroll")                                                       \
        for (int k = 2; k <= 16; k <<= 1) {                                     \
            _Pragma("unroll")                                                   \
            for (int s = k >> 1; s >= 1; s >>= 1) {                             \
                const float other = __shfl_xor(v, s, 64);                       \
                const bool lower = ((j & s) == 0);                              \
                const bool up    = ((j & k) == 0);                              \
                v = (lower == up) ? fmaxf(v, other) : fminf(v, other);          \
            }                                                                   \
        }                                                                       \
        float cs = v, css = v * v;                                              \
        _Pragma("unroll")                                                       \
        for (int off = 1; off < 16; off <<= 1) {                                \
            const int src = gb + ((j >= off) ? (j - off) : 0);                  \
            const float t1 = __shfl(cs,  src, 64);                              \
            const float t2 = __shfl(css, src, 64);                              \
            if (j >= off) { cs += t1; css += t2; }                              \
        }                                                                       \
        const float kkf    = (float)(j + 1);                                    \
        const float mean   = cs / kkf;                                          \
        const float meansq = css / kkf;                                         \
        const float ssv    = kkf * (meansq - mean * mean);                      \
        const float delta  = (1.f - ssv) / kkf;                                 \
        const float sq     = (delta > 0.f) ? sqrtf(delta) : 0.f;                \
        const float tau    = mean - sq;                                         \
        const unsigned long long bal = __ballot(tau <= v);                      \
        const int supp = (int)__popcll((bal >> gb) & 0xFFFFull);                \
        const float tau_star = __shfl(tau, gb + supp - 1, 64);                  \
        const float y = fmaxf(x - tau_star, 0.f);                               \
        w_lds[wid][BUF][lane]  = y * y;                                         \
        nb_lds[wid][BUF][lane] = nbj;                                           \
    }

    // ---- issue 8 z-gathers for batch at slice BUF into named regs
    #define ISSUE(BUF, ZA, AWA)                                                 \
    _Pragma("unroll")                                                           \
    for (int i = 0; i < 4; ++i) {                                               \
        const int   j0 = nb_lds[wid][BUF][i * 16 + g];                          \
        const int   j1 = nb_lds[wid][BUF][i * 16 + 8 + g];                      \
        AWA[2 * i]     = w_lds[wid][BUF][i * 16 + g];                           \
        AWA[2 * i + 1] = w_lds[wid][BUF][i * 16 + 8 + g];                       \
        ZA[2 * i]     = *reinterpret_cast<const u32x4*>(zs + (size_t)j0 * OUTDIM + c8 * 8); \
        ZA[2 * i + 1] = *reinterpret_cast<const u32x4*>(zs + (size_t)j1 * OUTDIM + c8 * 8); \
    }

    #define ACC2(av, zv)                                               \
        w.u = (zv)[0] << 16;         acc[0] = fmaf(av, w.f, acc[0]);   \
        w.u = (zv)[0] & 0xFFFF0000u; acc[1] = fmaf(av, w.f, acc[1]);   \
        w.u = (zv)[1] << 16;         acc[2] = fmaf(av, w.f, acc[2]);   \
        w.u = (zv)[1] & 0xFFFF0000u; acc[3] = fmaf(av, w.f, acc[3]);   \
        w.u = (zv)[2] << 16;         acc[4] = fmaf(av, w.f, acc[4]);   \
        w.u = (zv)[2] & 0xFFFF0000u; acc[5] = fmaf(av, w.f, acc[5]);   \
        w.u = (zv)[3] << 16;         acc[6] = fmaf(av, w.f, acc[6]);   \
        w.u = (zv)[3] & 0xFFFF0000u; acc[7] = fmaf(av, w.f, acc[7]);

    // ---- consume: unpack, FMA, cross-lane reduce, store
    #define CONSUME(ZA, AWA, BASE)                                              \
    _Pragma("unroll")                                                           \
    for (int i = 0; i < 4; ++i) {                                               \
        const int node = (BASE) + i;                                            \
        float acc[8] = {0.f, 0.f, 0.f, 0.f, 0.f, 0.f, 0.f, 0.f};               \
        union { unsigned u; float f; } w;                                       \
        ACC2(AWA[2 * i], ZA[2 * i])                                             \
        ACC2(AWA[2 * i + 1], ZA[2 * i + 1])                                     \
        _Pragma("unroll")                                                       \
        for (int c = 0; c < 8; ++c) {                                           \
            acc[c] += __shfl_xor(acc[c], 8, 64);                                \
            acc[c] += __shfl_xor(acc[c], 16, 64);                               \
            acc[c] += __shfl_xor(acc[c], 32, 64);                               \
        }                                                                       \
        if (g == 0 && node < n) {                                               \
            float* orow = out + (size_t)node * OUTDIM + c8 * 8;                 \
            *reinterpret_cast<float4*>(orow)     = make_float4(acc[0], acc[1], acc[2], acc[3]); \
            *reinterpret_cast<float4*>(orow + 4) = make_float4(acc[4], acc[5], acc[6], acc[7]); \
        }                                                                       \
    }

    u32x4 z0[8], z1[8];
    float aw0[8], aw1[8];

    ENTMAX(base0, 0)
    ISSUE(0, z0, aw0)          // 8 gathers in flight...
    ENTMAX(base1, 1)           // ...entmax b1 overlaps their latency
    CONSUME(z0, aw0, base0)
    ISSUE(1, z1, aw1)
    CONSUME(z1, aw1, base1)

    #undef ENTMAX
    #undef ISSUE
    #undef ACC2
    #undef CONSUME
}

extern "C" void kernel_launch(void* const* d_in, const int* in_sizes, int n_in,
                              void* d_out, int out_size, void* d_ws, size_t ws_size,
                              hipStream_t stream) {
    const float* h      = (const float*)d_in[0];
    const int*   nbr    = (const int*)  d_in[1];
    const float* wbias  = (const float*)d_in[2];
    const float* W_fc   = (const float*)d_in[3];
    const float* W_attn = (const float*)d_in[4];
    float* out = (float*)d_out;

    const int n = in_sizes[0] / INDIM;   // 100000

    // ws: zb (n*64 bf16) | s_src (n f32) | s_dst (n f32)
    __hip_bfloat16* zb = (__hip_bfloat16*)d_ws;
    float* s_src = (float*)((char*)d_ws + (size_t)n * OUTDIM * sizeof(__hip_bfloat16));
    float* s_dst = s_src + n;

    fc_mfma<<<(n + 63) / 64, 256, 0, stream>>>(h, W_fc, W_attn, zb, s_src, s_dst, n);
    const int waves = (n + 7) / 8;
    fused_out<<<(waves + 3) / 4, 256, 0, stream>>>(nbr, wbias, zb, s_src, s_dst, out, n);
}

// Round 12
// 60.027 us; speedup vs baseline: 1.0184x; 1.0184x over previous
//
#include <hip/hip_runtime.h>
#include <hip/hip_bf16.h>

#define DNBR   16
#define INDIM  128
#define OUTDIM 64

typedef __attribute__((ext_vector_type(8))) short bf16x8;
typedef __attribute__((ext_vector_type(4))) float f32x4;
typedef __attribute__((ext_vector_type(4))) unsigned u32x4;

union BF8 { bf16x8 v; u32x4 u; };

__device__ __forceinline__ unsigned cvt_pk_bf16(float lo, float hi) {
    unsigned r;
    asm("v_cvt_pk_bf16_f32 %0, %1, %2" : "=v"(r) : "v"(lo), "v"(hi));
    return r;
}

// ---------------- Phase 1: z = h @ W_fc^T via bf16 MFMA, + s_src/s_dst -------
// W_fc converted to MFMA B-fragment order in LDS per block.
__global__ __launch_bounds__(256) void fc_mfma(
    const float* __restrict__ h, const float* __restrict__ W_fc,
    const float* __restrict__ W_attn, __hip_bfloat16* __restrict__ zb,
    float* __restrict__ s_src, float* __restrict__ s_dst, int n)
{
    __shared__ unsigned wl[4096];   // 16 KB: slot(ct,kk,lane) -> 4 u32 (8 bf16)

    const int tid = threadIdx.x;
    #pragma unroll
    for (int s4 = 0; s4 < 4; ++s4) {
        const int slot = tid + 256 * s4;      // 0..1023
        const int lane_s = slot & 63;
        const int ckk  = slot >> 6;           // ct*4+kk
        const int ct_s = ckk >> 2, kk_s = ckk & 3;
        const int lm_s = lane_s & 15, lg_s = lane_s >> 4;
        const float* wr = W_fc + (size_t)(ct_s * 16 + lm_s) * INDIM + kk_s * 32 + lg_s * 8;
        const float4 w0 = *reinterpret_cast<const float4*>(wr);
        const float4 w1 = *reinterpret_cast<const float4*>(wr + 4);
        wl[slot * 4 + 0] = cvt_pk_bf16(w0.x, w0.y);
        wl[slot * 4 + 1] = cvt_pk_bf16(w0.z, w0.w);
        wl[slot * 4 + 2] = cvt_pk_bf16(w1.x, w1.y);
        wl[slot * 4 + 3] = cvt_pk_bf16(w1.z, w1.w);
    }
    __syncthreads();

    const int lane  = threadIdx.x & 63;
    const int wid   = threadIdx.x >> 6;
    const int node0 = blockIdx.x * 64 + wid * 16;
    if (node0 >= n) return;
    const int lm = lane & 15;
    const int lg = lane >> 4;

    bf16x8 bfrag[4][4];
    #pragma unroll
    for (int ct = 0; ct < 4; ++ct)
        #pragma unroll
        for (int kk = 0; kk < 4; ++kk) {
            BF8 u;
            u.u = *reinterpret_cast<const u32x4*>(&wl[(size_t)((ct * 4 + kk) * 64 + lane) * 4]);
            bfrag[ct][kk] = u.v;
        }

    const int arow = (node0 + lm < n) ? (node0 + lm) : (n - 1);
    const float* hr = h + (size_t)arow * INDIM;
    bf16x8 af[4];
    #pragma unroll
    for (int kk = 0; kk < 4; ++kk) {
        const float4 a0 = *reinterpret_cast<const float4*>(hr + kk * 32 + lg * 8);
        const float4 a1 = *reinterpret_cast<const float4*>(hr + kk * 32 + lg * 8 + 4);
        BF8 u;
        u.u[0] = cvt_pk_bf16(a0.x, a0.y);
        u.u[1] = cvt_pk_bf16(a0.z, a0.w);
        u.u[2] = cvt_pk_bf16(a1.x, a1.y);
        u.u[3] = cvt_pk_bf16(a1.z, a1.w);
        af[kk] = u.v;
    }

    f32x4 acc[4];
    #pragma unroll
    for (int ct = 0; ct < 4; ++ct) acc[ct] = (f32x4){0.f, 0.f, 0.f, 0.f};
    #pragma unroll
    for (int kk = 0; kk < 4; ++kk)
        #pragma unroll
        for (int ct = 0; ct < 4; ++ct)
            acc[ct] = __builtin_amdgcn_mfma_f32_16x16x32_bf16(af[kk], bfrag[ct][kk], acc[ct], 0, 0, 0);

    float ps[4] = {0.f, 0.f, 0.f, 0.f};
    float pd[4] = {0.f, 0.f, 0.f, 0.f};
    unsigned short* zbs = reinterpret_cast<unsigned short*>(zb);
    #pragma unroll
    for (int ct = 0; ct < 4; ++ct) {
        const float as = W_attn[ct * 16 + lm];
        const float ad = W_attn[OUTDIM + ct * 16 + lm];
        #pragma unroll
        for (int r = 0; r < 4; ++r) {
            const float v = acc[ct][r];                 // C[(lg*4+r)][ct*16+lm]
            const int grow = node0 + lg * 4 + r;
            if (grow < n)
                zbs[(size_t)grow * OUTDIM + ct * 16 + lm] =
                    (unsigned short)(cvt_pk_bf16(v, v) & 0xFFFFu);
            ps[r] = fmaf(v, as, ps[r]);
            pd[r] = fmaf(v, ad, pd[r]);
        }
    }
    #pragma unroll
    for (int off = 1; off < 16; off <<= 1) {
        #pragma unroll
        for (int r = 0; r < 4; ++r) {
            ps[r] += __shfl_xor(ps[r], off, 64);
            pd[r] += __shfl_xor(pd[r], off, 64);
        }
    }
    if (lm == 0) {
        #pragma unroll
        for (int r = 0; r < 4; ++r) {
            const int grow = node0 + lg * 4 + r;
            if (grow < n) { s_src[grow] = ps[r]; s_dst[grow] = pd[r]; }
        }
    }
}

// ---------------- Phase 2: fused entmax + SPARSE gather ----------------------
// Wave owns 4 nodes. Lane-parallel entmax (16-lane group per node) computes
// weights; nonzero (w, idx) pairs are COMPACTED into LDS; gather phase loads
// only the support (entmax-1.5 is sparse: typical support ~3-6 of 16), cutting
// random z-line traffic proportionally. Zero-weight terms are exactly zero.
__global__ __launch_bounds__(256) void fused_out(
    const int* __restrict__ nbr, const float* __restrict__ wbias,
    const __hip_bfloat16* __restrict__ zb, const float* __restrict__ s_src,
    const float* __restrict__ s_dst, float* __restrict__ out, int n)
{
    __shared__ float w_lds[4][64];
    __shared__ int  nb_lds[4][64];
    __shared__ int  cnt_lds[4][4];

    const int lane = threadIdx.x & 63;
    const int wid  = threadIdx.x >> 6;
    const int wv   = blockIdx.x * 4 + wid;
    const int base = wv * 4;
    if (base >= n) return;

    // ---- entmax phase: group q = lane>>4 handles node base+q, slot j=lane&15
    {
        const int q = lane >> 4;
        const int j = lane & 15;
        const int gb = lane & 48;            // group base lane
        const int node_q = base + q;
        const int nq = (node_q < n) ? node_q : n - 1;

        const int   nbj = nbr  [(size_t)nq * DNBR + j];
        const float wj  = wbias[(size_t)nq * DNBR + j];
        const float sd  = s_dst[nq];
        float e = s_src[nbj] + sd;
        e = (e >= 0.f) ? e : 0.01f * e;
        float x = 0.5f * (e + wj);

        // group max, subtract
        float m = x;
        m = fmaxf(m, __shfl_xor(m, 1, 64));
        m = fmaxf(m, __shfl_xor(m, 2, 64));
        m = fmaxf(m, __shfl_xor(m, 4, 64));
        m = fmaxf(m, __shfl_xor(m, 8, 64));
        x -= m;

        // bitonic sort DESCENDING across the 16-lane group
        float v = x;
        #pragma unroll
        for (int k = 2; k <= 16; k <<= 1) {
            #pragma unroll
            for (int s = k >> 1; s >= 1; s >>= 1) {
                const float other = __shfl_xor(v, s, 64);
                const bool lower = ((j & s) == 0);
                const bool up    = ((j & k) == 0);
                v = (lower == up) ? fmaxf(v, other) : fminf(v, other);
            }
        }

        // inclusive scans of v and v^2 over ranks 0..j
        float cs = v, css = v * v;
        #pragma unroll
        for (int off = 1; off < 16; off <<= 1) {
            const int src = gb + ((j >= off) ? (j - off) : 0);
            const float t1 = __shfl(cs,  src, 64);
            const float t2 = __shfl(css, src, 64);
            if (j >= off) { cs += t1; css += t2; }
        }

        const float kkf    = (float)(j + 1);
        const float mean   = cs / kkf;
        const float meansq = css / kkf;
        const float ssv    = kkf * (meansq - mean * mean);
        const float delta  = (1.f - ssv) / kkf;
        const float sq     = (delta > 0.f) ? sqrtf(delta) : 0.f;
        const float tau    = mean - sq;

        const unsigned long long bal = __ballot(tau <= v);
        const int supp = (int)__popcll((bal >> gb) & 0xFFFFull);
        const float tau_star = __shfl(tau, gb + supp - 1, 64);

        const float y = fmaxf(x - tau_star, 0.f);
        const float y2 = y * y;

        // compact nonzero (y2, nbj) pairs to the front of the group's 16 slots
        const unsigned long long nz = __ballot(y2 > 0.f);
        const unsigned grpmask = (unsigned)((nz >> gb) & 0xFFFFull);
        const int rank = __popc(grpmask & ((1u << j) - 1u));
        if (y2 > 0.f) {
            w_lds[wid][gb + rank]  = y2;
            nb_lds[wid][gb + rank] = nbj;
        }
        if (j == 0) cnt_lds[wid][q] = __popc(grpmask);
    }
    // same-wave LDS handoff (DS ops in program order within a wave)

    // ---- sparse gather phase: only cnt slots per node are loaded
    const int g  = lane >> 3;
    const int c8 = lane & 7;
    const unsigned short* zs = reinterpret_cast<const unsigned short*>(zb);

    #pragma unroll
    for (int i = 0; i < 4; ++i) {
        const int node = base + i;
        const int cnt = cnt_lds[wid][i];

        float acc[8] = {0.f, 0.f, 0.f, 0.f, 0.f, 0.f, 0.f, 0.f};
        union { unsigned u; float f; } w;
        #define ACC2(av, zv)                                               \
            w.u = (zv)[0] << 16;         acc[0] = fmaf(av, w.f, acc[0]);   \
            w.u = (zv)[0] & 0xFFFF0000u; acc[1] = fmaf(av, w.f, acc[1]);   \
            w.u = (zv)[1] << 16;         acc[2] = fmaf(av, w.f, acc[2]);   \
            w.u = (zv)[1] & 0xFFFF0000u; acc[3] = fmaf(av, w.f, acc[3]);   \
            w.u = (zv)[2] << 16;         acc[4] = fmaf(av, w.f, acc[4]);   \
            w.u = (zv)[2] & 0xFFFF0000u; acc[5] = fmaf(av, w.f, acc[5]);   \
            w.u = (zv)[3] << 16;         acc[6] = fmaf(av, w.f, acc[6]);   \
            w.u = (zv)[3] & 0xFFFF0000u; acc[7] = fmaf(av, w.f, acc[7]);

        if (g < cnt) {
            const int   j0  = nb_lds[wid][i * 16 + g];
            const float a0w = w_lds[wid][i * 16 + g];
            const u32x4 z0 = *reinterpret_cast<const u32x4*>(zs + (size_t)j0 * OUTDIM + c8 * 8);
            ACC2(a0w, z0)
        }
        if (8 + g < cnt) {
            const int   j1  = nb_lds[wid][i * 16 + 8 + g];
            const float a1w = w_lds[wid][i * 16 + 8 + g];
            const u32x4 z1 = *reinterpret_cast<const u32x4*>(zs + (size_t)j1 * OUTDIM + c8 * 8);
            ACC2(a1w, z1)
        }
        #undef ACC2

        #pragma unroll
        for (int c = 0; c < 8; ++c) {
            acc[c] += __shfl_xor(acc[c], 8, 64);
            acc[c] += __shfl_xor(acc[c], 16, 64);
            acc[c] += __shfl_xor(acc[c], 32, 64);
        }

        if (g == 0 && node < n) {
            float* orow = out + (size_t)node * OUTDIM + c8 * 8;
            *reinterpret_cast<float4*>(orow)     = make_float4(acc[0], acc[1], acc[2], acc[3]);
            *reinterpret_cast<float4*>(orow + 4) = make_float4(acc[4], acc[5], acc[6], acc[7]);
        }
    }
}

extern "C" void kernel_launch(void* const* d_in, const int* in_sizes, int n_in,
                              void* d_out, int out_size, void* d_ws, size_t ws_size,
                              hipStream_t stream) {
    const float* h      = (const float*)d_in[0];
    const int*   nbr    = (const int*)  d_in[1];
    const float* wbias  = (const float*)d_in[2];
    const float* W_fc   = (const float*)d_in[3];
    const float* W_attn = (const float*)d_in[4];
    float* out = (float*)d_out;

    const int n = in_sizes[0] / INDIM;   // 100000

    // ws: zb (n*64 bf16) | s_src (n f32) | s_dst (n f32)
    __hip_bfloat16* zb = (__hip_bfloat16*)d_ws;
    float* s_src = (float*)((char*)d_ws + (size_t)n * OUTDIM * sizeof(__hip_bfloat16));
    float* s_dst = s_src + n;

    fc_mfma<<<(n + 63) / 64, 256, 0, stream>>>(h, W_fc, W_attn, zb, s_src, s_dst, n);
    fused_out<<<(n + 15) / 16, 256, 0, stream>>>(nbr, wbias, zb, s_src, s_dst, out, n);
}